// Round 1
// baseline (588.856 us; speedup 1.0000x reference)
//
#include <hip/hip_runtime.h>
#include <hip/hip_bf16.h>
#include <stdint.h>

// GroupedQAttention on MI355X.
// Pipeline: cast x->bf16, transpose-cast w_qkvw/w_out -> bf16 BT,
//           GEMM1 (bf16 MFMA) -> qkvw, fused tiny-attention + *w -> ow (bf16),
//           GEMM2 (bf16 MFMA) -> fp32 out.
// GEMM structure = guide m97 (128x128 tile, BK=32, 4 waves, global_load_lds x16).

typedef __bf16 bf16;
typedef __bf16 bf16x8 __attribute__((ext_vector_type(8)));
typedef float f32x4 __attribute__((ext_vector_type(4)));

__device__ __forceinline__ void gload16(const bf16* g, bf16* l) {
  __builtin_amdgcn_global_load_lds(
      (const __attribute__((address_space(1))) void*)g,
      (__attribute__((address_space(3))) void*)l, 16, 0, 0);
}

// ---------------- GEMM: C[M][N] = A[M][1024] * BT[N][1024]^T ----------------
template <typename OutT>
__global__ __launch_bounds__(256)
void gemm_bt(const bf16* __restrict__ A, const bf16* __restrict__ BT,
             OutT* __restrict__ C, int N) {
  constexpr int K = 1024;
  __shared__ bf16 lA[128 * 32];
  __shared__ bf16 lB[128 * 32];

  const int tid = threadIdx.x;
  const int lane = tid & 63;
  const int wv = tid >> 6;
  const long row0 = (long)blockIdx.y * 128;
  const long col0 = (long)blockIdx.x * 128;

  // staging: per wave, 2 global_load_lds per operand; LDS linear [128][32]
  bf16* ldsA = lA + wv * 512;
  bf16* ldsB = lB + wv * 512;
  const long srow = wv * 16 + (lane >> 2);
  const int scol = (lane & 3) * 8;
  const bf16* gA0 = A + (row0 + srow) * K + scol;
  const bf16* gA1 = A + (row0 + srow + 64) * K + scol;
  const bf16* gB0 = BT + (col0 + srow) * K + scol;
  const bf16* gB1 = BT + (col0 + srow + 64) * K + scol;

  const int wr = (wv >> 1) * 64;   // wave's 64x64 quadrant
  const int wc = (wv & 1) * 64;
  const int fr = lane & 15;        // fragment row (A) / col (B)
  const int fk = (lane >> 4) * 8;  // k-slice

  f32x4 acc[4][4] = {};

  for (int k = 0; k < K; k += 32) {
    __syncthreads();
    gload16(gA0 + k, ldsA);
    gload16(gA1 + k, ldsA + 2048);
    gload16(gB0 + k, ldsB);
    gload16(gB1 + k, ldsB + 2048);
    __syncthreads();
    bf16x8 av[4], bv[4];
#pragma unroll
    for (int m = 0; m < 4; ++m)
      av[m] = *(const bf16x8*)&lA[(wr + m * 16 + fr) * 32 + fk];
#pragma unroll
    for (int n = 0; n < 4; ++n)
      bv[n] = *(const bf16x8*)&lB[(wc + n * 16 + fr) * 32 + fk];
#pragma unroll
    for (int m = 0; m < 4; ++m)
#pragma unroll
      for (int n = 0; n < 4; ++n)
        acc[m][n] = __builtin_amdgcn_mfma_f32_16x16x32_bf16(av[m], bv[n], acc[m][n], 0, 0, 0);
  }

  // C/D layout: col = lane&15, row = (lane>>4)*4 + reg   [guide m89/m91]
  const int crow = (lane >> 4) * 4;
  const int ccol = lane & 15;
#pragma unroll
  for (int m = 0; m < 4; ++m)
#pragma unroll
    for (int n = 0; n < 4; ++n) {
      const long r = row0 + wr + m * 16 + crow;
      const long c = col0 + wc + n * 16 + ccol;
#pragma unroll
      for (int i = 0; i < 4; ++i)
        C[(r + i) * (long)N + c] = (OutT)acc[m][n][i];
    }
}

// ---------------- fused tiny attention ----------------
__device__ __forceinline__ void load16f(const bf16* p, float* f) {
  const uint4* u = (const uint4*)p;
  uint4 a = u[0], b = u[1];
  uint32_t w[8] = {a.x, a.y, a.z, a.w, b.x, b.y, b.z, b.w};
#pragma unroll
  for (int j = 0; j < 8; ++j) {
    f[2 * j] = __uint_as_float(w[j] << 16);
    f[2 * j + 1] = __uint_as_float(w[j] & 0xffff0000u);
  }
}

// block = (s_hi, g, bz); 256 threads = 16 s_lo x 16 h1
__global__ __launch_bounds__(256)
void attn_fuse(const bf16* __restrict__ qkvw, bf16* __restrict__ ow,
               int b0, long bstride) {
  __shared__ bf16 data[16 * 1024];
  const int s_hi = blockIdx.x;
  const int g = blockIdx.y;
  const int bz = blockIdx.z;
  const int b = b0 + bz;
  const bf16* base = qkvw + (long)bz * bstride;
  const int tid = threadIdx.x;

#pragma unroll
  for (int i = 0; i < 8; ++i) {
    int c = tid + i * 256;
    int h = c >> 7;
    int col = (c & 127) * 8;
    *(uint4*)&data[h * 1024 + col] =
        *(const uint4*)(base + (long)(h * 256 + s_hi) * 4096 + g * 1024 + col);
  }
  __syncthreads();

  const int s_lo = tid >> 4;
  const int h1 = tid & 15;
  const int off = s_lo * 16;

  float q[16], p[16], o[16];
  load16f(&data[h1 * 1024 + off], q);

  float mx = -1e30f;
#pragma unroll
  for (int h2 = 0; h2 < 16; ++h2) {
    float kf[16];
    load16f(&data[h2 * 1024 + 256 + off], kf);
    float s = 0.f;
#pragma unroll
    for (int d = 0; d < 16; ++d) s += q[d] * kf[d];
    s *= 0.25f;  // HD^-0.5, HD=16
    p[h2] = s;
    mx = fmaxf(mx, s);
  }
  float sum = 0.f;
#pragma unroll
  for (int h2 = 0; h2 < 16; ++h2) {
    float e = __expf(p[h2] - mx);
    p[h2] = e;
    sum += e;
  }
  const float inv = 1.f / sum;
#pragma unroll
  for (int d = 0; d < 16; ++d) o[d] = 0.f;
#pragma unroll
  for (int h2 = 0; h2 < 16; ++h2) {
    float vf[16];
    load16f(&data[h2 * 1024 + 512 + off], vf);
    const float a = p[h2] * inv;
#pragma unroll
    for (int d = 0; d < 16; ++d) o[d] += a * vf[d];
  }
  float wf[16];
  load16f(&data[h1 * 1024 + 768 + off], wf);

  const int bp = g * 8 + b;  // concat index along axis 0
  const long R = (long)(bp >> 2) * 4096 + (bp & 3) * 1024 + h1 * 64 + (s_hi >> 2);
  const int cb = (s_hi & 3) * 256 + off;
  union { uint4 u[2]; bf16 hh[16]; } st;
#pragma unroll
  for (int d = 0; d < 16; ++d) st.hh[d] = (bf16)(o[d] * wf[d]);
  uint4* dst = (uint4*)&ow[R * 1024 + cb];
  dst[0] = st.u[0];
  dst[1] = st.u[1];
}

// ---------------- casts ----------------
__global__ __launch_bounds__(256)
void cast_x_kernel(const float* __restrict__ in, bf16* __restrict__ out, long n4) {
  long i = (long)blockIdx.x * 256 + threadIdx.x;
  if (i >= n4) return;
  float4 v = ((const float4*)in)[i];
  union { uint2 d; bf16 h[4]; } r;
  r.h[0] = (bf16)v.x; r.h[1] = (bf16)v.y; r.h[2] = (bf16)v.z; r.h[3] = (bf16)v.w;
  ((uint2*)out)[i] = r.d;
}

// out[C][R] = bf16(in[R][C])  (transpose-cast, 64x64 tiles)
__global__ __launch_bounds__(256)
void tcast_kernel(const float* __restrict__ in, bf16* __restrict__ out, int R, int C) {
  __shared__ float t[64][65];
  const int c0 = blockIdx.x * 64, r0 = blockIdx.y * 64;
  const int lr = threadIdx.x >> 6;
  const int lc = threadIdx.x & 63;
#pragma unroll
  for (int i = 0; i < 16; ++i)
    t[lr + i * 4][lc] = in[(long)(r0 + lr + i * 4) * C + c0 + lc];
  __syncthreads();
#pragma unroll
  for (int i = 0; i < 16; ++i) {
    int oc = lr + i * 4;
    out[(long)(c0 + oc) * R + r0 + lc] = (bf16)t[lc][oc];
  }
}

// ---------------- launch ----------------
extern "C" void kernel_launch(void* const* d_in, const int* in_sizes, int n_in,
                              void* d_out, int out_size, void* d_ws, size_t ws_size,
                              hipStream_t stream) {
  const float* x = (const float*)d_in[0];
  const float* w_qkvw = (const float*)d_in[1];
  const float* w_out = (const float*)d_in[2];
  float* out = (float*)d_out;

  char* ws = (char*)d_ws;
  size_t off = 0;
  bf16* x_bf = (bf16*)(ws + off); off += (size_t)32768 * 1024 * 2;
  bf16* bt1  = (bf16*)(ws + off); off += (size_t)4096 * 1024 * 2;
  bf16* bt2  = (bf16*)(ws + off); off += (size_t)1024 * 1024 * 2;
  bf16* owb  = (bf16*)(ws + off); off += (size_t)32768 * 1024 * 2;
  bf16* qk   = (bf16*)(ws + off);
  const size_t rem = ws_size > off ? ws_size - off : 0;
  const size_t full_need = (size_t)32768 * 4096 * 2;

  cast_x_kernel<<<32768, 256, 0, stream>>>(x, x_bf, (long)8388608);
  tcast_kernel<<<dim3(64, 16), 256, 0, stream>>>(w_qkvw, bt1, 1024, 4096);
  tcast_kernel<<<dim3(16, 16), 256, 0, stream>>>(w_out, bt2, 1024, 1024);

  if (rem >= full_need) {
    gemm_bt<bf16><<<dim3(32, 256), 256, 0, stream>>>(x_bf, bt1, qk, 4096);
    attn_fuse<<<dim3(256, 4, 8), 256, 0, stream>>>(qk, owb, 0, (long)4096 * 4096);
  } else {
    for (int b = 0; b < 8; ++b) {
      gemm_bt<bf16><<<dim3(32, 32), 256, 0, stream>>>(
          x_bf + (size_t)b * 4096 * 1024, bt1, qk, 4096);
      attn_fuse<<<dim3(256, 4, 1), 256, 0, stream>>>(qk, owb, b, 0);
    }
  }
  gemm_bt<float><<<dim3(8, 256), 256, 0, stream>>>(owb, bt2, out, 1024);
}

// Round 2
// 478.448 us; speedup vs baseline: 1.2308x; 1.2308x over previous
//
#include <hip/hip_runtime.h>
#include <hip/hip_bf16.h>
#include <stdint.h>

// GroupedQAttention on MI355X.
// cast x->bf16, transpose-cast weights -> bf16 BT,
// GEMM1 (256^2 8-phase bf16 MFMA) -> qkvw, fused tiny-attention*w -> ow (bf16),
// GEMM2 (256^2 8-phase) -> fp32 out.

typedef __bf16 bf16;
typedef __bf16 bf16x8 __attribute__((ext_vector_type(8)));
typedef float f32x4 __attribute__((ext_vector_type(4)));

__device__ __forceinline__ void gload16(const bf16* g, bf16* l) {
  __builtin_amdgcn_global_load_lds(
      (const __attribute__((address_space(1))) void*)g,
      (__attribute__((address_space(3))) void*)l, 16, 0, 0);
}

#define BAR() asm volatile("s_barrier" ::: "memory")
#define SB() __builtin_amdgcn_sched_barrier(0)

// ---------- 256x256-tile 8-phase GEMM: C[M][N] = A[M][1024] * BT[N][1024]^T ----
// 512 threads = 8 waves (2Mx4N). BK=64, 16 K-tiles. LDS 128KiB double-buffered.
// Swizzle involution on [128][64]bf16 halves: byte ^= ((byte>>7)&7)<<4.
#define READ_A(mq)                                                            \
  {                                                                           \
    _Pragma("unroll") for (int i = 0; i < 4; ++i)                             \
        _Pragma("unroll") for (int kk = 0; kk < 2; ++kk)                      \
            a[i][kk] = *(const bf16x8*)(lds + aoff +                          \
                                        ((mq)*64 + i * 16 + fr) * 128 +       \
                                        ((kk * 64 + fkb) ^ xo));              \
  }
#define READ_B(nh)                                                            \
  {                                                                           \
    _Pragma("unroll") for (int j = 0; j < 2; ++j)                             \
        _Pragma("unroll") for (int kk = 0; kk < 2; ++kk)                      \
            b[(nh)*2 + j][kk] = *(const bf16x8*)(lds + boff +                 \
                                                 (bro + (nh)*32 + j * 16 + fr) * 128 + \
                                                 ((kk * 64 + fkb) ^ xo));     \
  }
#define MFMA_Q(mq, nh)                                                        \
  {                                                                           \
    _Pragma("unroll") for (int i = 0; i < 4; ++i)                             \
        _Pragma("unroll") for (int j = 0; j < 2; ++j) {                       \
      acc[(mq)*4 + i][(nh)*2 + j] = __builtin_amdgcn_mfma_f32_16x16x32_bf16(  \
          a[i][0], b[(nh)*2 + j][0], acc[(mq)*4 + i][(nh)*2 + j], 0, 0, 0);   \
      acc[(mq)*4 + i][(nh)*2 + j] = __builtin_amdgcn_mfma_f32_16x16x32_bf16(  \
          a[i][1], b[(nh)*2 + j][1], acc[(mq)*4 + i][(nh)*2 + j], 0, 0, 0);   \
    }                                                                         \
  }
#define STAGE_A(h, X)                                                         \
  {                                                                           \
    const int ro = ((X)&1) * 65536 + (h)*16384;                               \
    const bf16* g = gA + ((h)*128) * 1024 + (X)*64;                           \
    gload16(g, (bf16*)(lds + ro + wv * 1024));                                \
    gload16(g + 64 * 1024, (bf16*)(lds + ro + 8192 + wv * 1024));             \
  }
#define STAGE_B(h, X)                                                         \
  {                                                                           \
    const int ro = ((X)&1) * 65536 + 32768 + (h)*16384;                       \
    const bf16* g = gB + ((h)*128) * 1024 + (X)*64;                           \
    gload16(g, (bf16*)(lds + ro + wv * 1024));                                \
    gload16(g + 64 * 1024, (bf16*)(lds + ro + 8192 + wv * 1024));             \
  }

template <typename OutT>
__global__ __launch_bounds__(512, 2)
void gemm256(const bf16* __restrict__ A, const bf16* __restrict__ BT,
             OutT* __restrict__ C, int N) {
  constexpr int K = 1024;
  __shared__ __align__(16) char smem[131072];
  char* lds = smem;

  const int tid = threadIdx.x;
  const int lane = tid & 63;
  const int wv = tid >> 6;
  const int wr = wv >> 2;  // 0..1
  const int wc = wv & 3;   // 0..3

  // bijective XCD swizzle (grid counts are multiples of 8)
  const int gx = gridDim.x;
  const int nwg = gx * gridDim.y;
  const int bid = blockIdx.y * gx + blockIdx.x;
  const int swz = (bid & 7) * (nwg >> 3) + (bid >> 3);
  const long row0 = (long)(swz / gx) * 256;
  const long col0 = (long)(swz % gx) * 256;

  // staging source (pre-swizzled so linear global_load_lds dest == swizzled layout)
  const int srow = tid >> 3;  // 0..63
  const int scol = (((tid & 7) * 16) ^ ((srow & 7) << 4)) >> 1;  // elements
  const bf16* gA = A + (row0 + srow) * K + scol;
  const bf16* gB = BT + (col0 + srow) * K + scol;

  // fragment read addressing
  const int fr = lane & 15;
  const int fkb = (lane >> 4) * 16;  // byte offset of k-slice
  const int xo = (fr & 7) << 4;
  const int bro = (wc & 1) * 64;

  bf16x8 a[4][2], b[4][2];
  f32x4 acc[8][4] = {};

  // prologue: tile0 all 4 halves + tile1 B halves; allow B(1) in flight
  STAGE_A(0, 0); STAGE_A(1, 0); STAGE_B(0, 0); STAGE_B(1, 0);
  STAGE_B(0, 1); STAGE_B(1, 1);
  asm volatile("s_waitcnt vmcnt(4)" ::: "memory");
  SB(); BAR(); SB();

  for (int T = 0; T < 16; ++T) {
    const int d = T & 1;
    const int aoff = d * 65536 + wr * 16384;
    const int boff = d * 65536 + 32768 + (wc >> 1) * 16384;
    // ph0: A-mlo + B-nlo reads; stage A-lo(T+1)
    READ_A(0); READ_B(0);
    if (T < 15) STAGE_A(0, T + 1);
    SB(); BAR(); SB();
    __builtin_amdgcn_s_setprio(1); MFMA_Q(0, 0); __builtin_amdgcn_s_setprio(0);
    SB(); BAR(); SB();
    // ph1: B-nhi reads; stage A-hi(T+1)
    READ_B(1);
    if (T < 15) STAGE_A(1, T + 1);
    SB(); BAR(); SB();
    __builtin_amdgcn_s_setprio(1); MFMA_Q(0, 1); __builtin_amdgcn_s_setprio(0);
    SB(); BAR(); SB();
    // ph2: A-mhi reads; stage B-lo(T+2)  (tile T's B dead after ph1-bar2)
    READ_A(1);
    if (T < 14) STAGE_B(0, T + 2);
    SB(); BAR(); SB();
    __builtin_amdgcn_s_setprio(1); MFMA_Q(1, 0); __builtin_amdgcn_s_setprio(0);
    SB(); BAR(); SB();
    // ph3: stage B-hi(T+2); counted vmcnt gate (tile T+1 fully landed)
    if (T < 14) {
      STAGE_B(1, T + 2);
      asm volatile("s_waitcnt vmcnt(4)" ::: "memory");
    } else if (T == 14) {
      asm volatile("s_waitcnt vmcnt(0)" ::: "memory");
    }
    SB(); BAR(); SB();
    __builtin_amdgcn_s_setprio(1); MFMA_Q(1, 1); __builtin_amdgcn_s_setprio(0);
    SB(); BAR(); SB();
  }

  // epilogue: C/D layout col=lane&15, row=(lane>>4)*4+reg
  const int crow = (lane >> 4) * 4;
  const int ccol = lane & 15;
  const long rb = row0 + wr * 128;
  const long cb = col0 + wc * 64;
#pragma unroll
  for (int m = 0; m < 8; ++m)
#pragma unroll
    for (int n = 0; n < 4; ++n)
#pragma unroll
      for (int i = 0; i < 4; ++i)
        C[(rb + m * 16 + crow + i) * (long)N + cb + n * 16 + ccol] =
            (OutT)acc[m][n][i];
}

// ---------------- fused tiny attention ----------------
__device__ __forceinline__ void load16f(const bf16* p, float* f) {
  const uint4* u = (const uint4*)p;
  uint4 a = u[0], b = u[1];
  uint32_t w[8] = {a.x, a.y, a.z, a.w, b.x, b.y, b.z, b.w};
#pragma unroll
  for (int j = 0; j < 8; ++j) {
    f[2 * j] = __uint_as_float(w[j] << 16);
    f[2 * j + 1] = __uint_as_float(w[j] & 0xffff0000u);
  }
}

// block = (s_hi, g, bz); 256 threads = 16 s_lo x 16 h1
__global__ __launch_bounds__(256)
void attn_fuse(const bf16* __restrict__ qkvw, bf16* __restrict__ ow,
               int b0, long bstride) {
  __shared__ bf16 data[16 * 1024];
  const int s_hi = blockIdx.x;
  const int g = blockIdx.y;
  const int bz = blockIdx.z;
  const int b = b0 + bz;
  const bf16* base = qkvw + (long)bz * bstride;
  const int tid = threadIdx.x;

#pragma unroll
  for (int i = 0; i < 8; ++i) {
    int c = tid + i * 256;
    int h = c >> 7;
    int col = (c & 127) * 8;
    *(uint4*)&data[h * 1024 + col] =
        *(const uint4*)(base + (long)(h * 256 + s_hi) * 4096 + g * 1024 + col);
  }
  __syncthreads();

  const int s_lo = tid >> 4;
  const int h1 = tid & 15;
  const int off = s_lo * 16;

  float q[16], p[16], o[16];
  load16f(&data[h1 * 1024 + off], q);

  float mx = -1e30f;
#pragma unroll
  for (int h2 = 0; h2 < 16; ++h2) {
    float kf[16];
    load16f(&data[h2 * 1024 + 256 + off], kf);
    float s = 0.f;
#pragma unroll
    for (int d = 0; d < 16; ++d) s += q[d] * kf[d];
    s *= 0.25f;  // HD^-0.5, HD=16
    p[h2] = s;
    mx = fmaxf(mx, s);
  }
  float sum = 0.f;
#pragma unroll
  for (int h2 = 0; h2 < 16; ++h2) {
    float e = __expf(p[h2] - mx);
    p[h2] = e;
    sum += e;
  }
  const float inv = 1.f / sum;
#pragma unroll
  for (int d = 0; d < 16; ++d) o[d] = 0.f;
#pragma unroll
  for (int h2 = 0; h2 < 16; ++h2) {
    float vf[16];
    load16f(&data[h2 * 1024 + 512 + off], vf);
    const float av = p[h2] * inv;
#pragma unroll
    for (int d = 0; d < 16; ++d) o[d] += av * vf[d];
  }
  float wf[16];
  load16f(&data[h1 * 1024 + 768 + off], wf);

  const int bp = g * 8 + b;  // concat index along axis 0
  const long R = (long)(bp >> 2) * 4096 + (bp & 3) * 1024 + h1 * 64 + (s_hi >> 2);
  const int cbo = (s_hi & 3) * 256 + off;
  union { uint4 u[2]; bf16 hh[16]; } st;
#pragma unroll
  for (int d = 0; d < 16; ++d) st.hh[d] = (bf16)(o[d] * wf[d]);
  uint4* dst = (uint4*)&ow[R * 1024 + cbo];
  dst[0] = st.u[0];
  dst[1] = st.u[1];
}

// ---------------- casts ----------------
__global__ __launch_bounds__(256)
void cast_x_kernel(const float* __restrict__ in, bf16* __restrict__ out, long n4) {
  long i = (long)blockIdx.x * 256 + threadIdx.x;
  if (i >= n4) return;
  float4 v = ((const float4*)in)[i];
  union { uint2 d; bf16 h[4]; } r;
  r.h[0] = (bf16)v.x; r.h[1] = (bf16)v.y; r.h[2] = (bf16)v.z; r.h[3] = (bf16)v.w;
  ((uint2*)out)[i] = r.d;
}

// out[C][R] = bf16(in[R][C])  (transpose-cast, 64x64 tiles)
__global__ __launch_bounds__(256)
void tcast_kernel(const float* __restrict__ in, bf16* __restrict__ out, int R, int C) {
  __shared__ float t[64][65];
  const int c0 = blockIdx.x * 64, r0 = blockIdx.y * 64;
  const int lr = threadIdx.x >> 6;
  const int lc = threadIdx.x & 63;
#pragma unroll
  for (int i = 0; i < 16; ++i)
    t[lr + i * 4][lc] = in[(long)(r0 + lr + i * 4) * C + c0 + lc];
  __syncthreads();
#pragma unroll
  for (int i = 0; i < 16; ++i) {
    int oc = lr + i * 4;
    out[(long)(c0 + oc) * R + r0 + lc] = (bf16)t[lc][oc];
  }
}

// ---------------- launch ----------------
extern "C" void kernel_launch(void* const* d_in, const int* in_sizes, int n_in,
                              void* d_out, int out_size, void* d_ws, size_t ws_size,
                              hipStream_t stream) {
  const float* x = (const float*)d_in[0];
  const float* w_qkvw = (const float*)d_in[1];
  const float* w_out = (const float*)d_in[2];
  float* out = (float*)d_out;

  char* ws = (char*)d_ws;
  size_t off = 0;
  bf16* x_bf = (bf16*)(ws + off); off += (size_t)32768 * 1024 * 2;
  bf16* bt1  = (bf16*)(ws + off); off += (size_t)4096 * 1024 * 2;
  bf16* bt2  = (bf16*)(ws + off); off += (size_t)1024 * 1024 * 2;
  bf16* owb  = (bf16*)(ws + off); off += (size_t)32768 * 1024 * 2;
  bf16* qk   = (bf16*)(ws + off);
  const size_t rem = ws_size > off ? ws_size - off : 0;
  const size_t full_need = (size_t)32768 * 4096 * 2;

  cast_x_kernel<<<32768, 256, 0, stream>>>(x, x_bf, (long)8388608);
  tcast_kernel<<<dim3(64, 16), 256, 0, stream>>>(w_qkvw, bt1, 1024, 4096);
  tcast_kernel<<<dim3(16, 16), 256, 0, stream>>>(w_out, bt2, 1024, 1024);

  if (rem >= full_need) {
    gemm256<bf16><<<dim3(16, 128), 512, 0, stream>>>(x_bf, bt1, qk, 4096);
    attn_fuse<<<dim3(256, 4, 8), 256, 0, stream>>>(qk, owb, 0, (long)4096 * 4096);
  } else {
    for (int b = 0; b < 8; ++b) {
      gemm256<bf16><<<dim3(16, 16), 512, 0, stream>>>(
          x_bf + (size_t)b * 4096 * 1024, bt1, qk, 4096);
      attn_fuse<<<dim3(256, 4, 1), 256, 0, stream>>>(qk, owb, b, 0);
    }
  }
  gemm256<float><<<dim3(4, 128), 512, 0, stream>>>(owb, bt2, out, 1024);
}